// Round 1
// baseline (1150.290 us; speedup 1.0000x reference)
//
#include <hip/hip_runtime.h>

// ---------------------------------------------------------------------------
// SpatialHead: coordconv(258->64,3x3)+BN+ReLU -> offsetconv(64->18,3x3)
//              -> deform_conv(64->64, 3x3 bilinear)+BN+ReLU
//              -> conv(64->64,3x3)+BN+ReLU -> conv(64->64,3x3)+BN+ReLU
//              -> 1x1 conv -> sigmoid
// B=8, H=W=96, fp32. Intermediates NHWC (channel-contiguous, C=64).
// ---------------------------------------------------------------------------

#define EPSBN 1e-5f

// ws layout in floats. x3 aliases x1 (x1 dead after deform).
#define X1_OFF   0u          // 8*96*96*64 = 4718592
#define OFF_OFF  4718592u    // offsets, padded to 64 ch
#define X2_OFF   9437184u
#define CWT_OFF  14155776u   // coord weights transposed [264][9][64] = 152064
#define OWT_OFF  (CWT_OFF + 152064u)   // [64][9][64] padded oc
#define R1WT_OFF (OWT_OFF + 36864u)
#define R2WT_OFF (R1WT_OFF + 36864u)
#define DCWT_OFF (R2WT_OFF + 36864u)   // [9][64][64] (k, ic, oc)
// total = 14155776 + 152064 + 4*36864 = 14455296 floats = 57.8 MB

// Transpose all weights into [c][tap][oc] (oc contiguous) layouts.
__global__ __launch_bounds__(256) void prep_weights(
    const float* __restrict__ coord_w, const float* __restrict__ off_w,
    const float* __restrict__ r1_w, const float* __restrict__ r2_w,
    const float* __restrict__ dc_w, float* __restrict__ ws)
{
  int d = blockIdx.x * 256 + threadIdx.x;
  if (d < 152064) {  // coord: 264 padded in-channels (258 real)
    int oc = d & 63; int r = d >> 6; int tap = r % 9; int c = r / 9;
    ws[CWT_OFF + d] = (c < 258) ? coord_w[(oc * 258 + c) * 9 + tap] : 0.f;
    return;
  }
  d -= 152064;
  if (d < 36864) {   // offset conv: oc padded 18 -> 64
    int oc = d & 63; int r = d >> 6; int tap = r % 9; int c = r / 9;
    ws[OWT_OFF + d] = (oc < 18) ? off_w[(oc * 64 + c) * 9 + tap] : 0.f;
    return;
  }
  d -= 36864;
  if (d < 36864) {
    int oc = d & 63; int r = d >> 6; int tap = r % 9; int c = r / 9;
    ws[R1WT_OFF + d] = r1_w[(oc * 64 + c) * 9 + tap];
    return;
  }
  d -= 36864;
  if (d < 36864) {
    int oc = d & 63; int r = d >> 6; int tap = r % 9; int c = r / 9;
    ws[R2WT_OFF + d] = r2_w[(oc * 64 + c) * 9 + tap];
    return;
  }
  d -= 36864;
  if (d < 36864) {   // dc: [k][ic][oc]
    int oc = d & 63; int r = d >> 6; int ic = r & 63; int k = r >> 6;
    ws[DCWT_OFF + d] = dc_w[(oc * 64 + ic) * 9 + k];
  }
}

// ---------------------------------------------------------------------------
// Direct 3x3 conv, pad=1. Block: 16x8 spatial tile x 64 oc, 256 threads.
// Thread = 8 oc x 4 px (32 accums). Input staged in LDS 8 channels at a time.
// ICP: padded input channels (multiple of 8). CS: global channel stride.
// COORD: channels 256/257 are virtual xx/yy coordinate maps.
// EPI: 0 = (+bias) +BN+ReLU -> NHWC64 ; 1 = +bias only (offset conv, oc<18
//      guarded) -> NHWC64 ; 2 = BN+ReLU + 1x1 outconv + sigmoid -> (B,96,96)
// ---------------------------------------------------------------------------
template<int ICP, int CS, bool COORD, int EPI>
__global__ __launch_bounds__(256, 2) void conv3x3_kernel(
    const float* __restrict__ in, const float* __restrict__ wt,
    const float* __restrict__ bias,
    const float* __restrict__ bng, const float* __restrict__ bnb,
    const float* __restrict__ bnm, const float* __restrict__ bnv,
    const float* __restrict__ ow, const float* __restrict__ ob,
    float* __restrict__ out)
{
  __shared__ __align__(16) float tile[8][10][20];  // [ic][y][x], x padded to 20
  const int t = threadIdx.x;
  const int x0 = blockIdx.x * 16, y0 = blockIdx.y * 8;
  const int b = blockIdx.z;
  const int pgrp = t & 31, ocb = t >> 5;
  const int gy = pgrp >> 2, gx = (pgrp & 3) * 4;
  const int oc0 = ocb * 8;
  float acc[8][4] = {};

  const int sy = t / 18, sx = t % 18;  // staging position (t < 180)
  const int sh_ = y0 + sy - 1, sw_ = x0 + sx - 1;
  const bool sinb = (t < 180) && ((unsigned)sh_ < 96u) && ((unsigned)sw_ < 96u);

  for (int c0 = 0; c0 < ICP; c0 += 8) {
    __syncthreads();
    if (t < 180) {
      float va[8];
      if (!COORD || c0 < 256) {
        if (sinb) {
          const float* p = in + ((size_t)((b * 96 + sh_) * 96 + sw_)) * CS + c0;
          const float4 a0 = *(const float4*)p;
          const float4 a1 = *(const float4*)(p + 4);
          va[0] = a0.x; va[1] = a0.y; va[2] = a0.z; va[3] = a0.w;
          va[4] = a1.x; va[5] = a1.y; va[6] = a1.z; va[7] = a1.w;
        } else {
          #pragma unroll
          for (int ci = 0; ci < 8; ++ci) va[ci] = 0.f;
        }
      } else {  // c0 == 256: virtual coordinate channels (zero-padded border!)
        #pragma unroll
        for (int ci = 0; ci < 8; ++ci) va[ci] = 0.f;
        if (sinb) {
          va[0] = -1.f + (2.f / 95.f) * (float)sw_;  // xx
          va[1] = -1.f + (2.f / 95.f) * (float)sh_;  // yy
        }
      }
      #pragma unroll
      for (int ci = 0; ci < 8; ++ci) tile[ci][sy][sx] = va[ci];
    }
    __syncthreads();

    #pragma unroll 2
    for (int ic = 0; ic < 8; ++ic) {
      const float* wrow = wt + (size_t)(c0 + ic) * 9 * 64 + oc0;
      #pragma unroll
      for (int kh = 0; kh < 3; ++kh) {
        const float4 i0 = *(const float4*)&tile[ic][gy + kh][gx];
        const float4 i1 = *(const float4*)&tile[ic][gy + kh][gx + 4];
        const float in8[8] = {i0.x, i0.y, i0.z, i0.w, i1.x, i1.y, i1.z, i1.w};
        #pragma unroll
        for (int kw = 0; kw < 3; ++kw) {
          const float* wp = wrow + (kh * 3 + kw) * 64;
          const float4 w0 = *(const float4*)wp;
          const float4 w1 = *(const float4*)(wp + 4);
          const float w8[8] = {w0.x, w0.y, w0.z, w0.w, w1.x, w1.y, w1.z, w1.w};
          #pragma unroll
          for (int i = 0; i < 8; ++i) {
            #pragma unroll
            for (int j = 0; j < 4; ++j)
              acc[i][j] = fmaf(w8[i], in8[j + kw], acc[i][j]);
          }
        }
      }
    }
  }

  const int oh = y0 + gy;
  const int ow0 = x0 + gx;

  if constexpr (EPI == 1) {
    float bs[8];
    #pragma unroll
    for (int i = 0; i < 8; ++i) {
      const int oc = oc0 + i;
      bs[i] = (oc < 18) ? bias[oc] : 0.f;
    }
    #pragma unroll
    for (int j = 0; j < 4; ++j) {
      float* op = out + ((size_t)((b * 96 + oh) * 96 + ow0 + j)) * 64 + oc0;
      *(float4*)op = make_float4(acc[0][j] + bs[0], acc[1][j] + bs[1],
                                 acc[2][j] + bs[2], acc[3][j] + bs[3]);
      *(float4*)(op + 4) = make_float4(acc[4][j] + bs[4], acc[5][j] + bs[5],
                                       acc[6][j] + bs[6], acc[7][j] + bs[7]);
    }
  } else {
    float sc[8], sh2[8];
    #pragma unroll
    for (int i = 0; i < 8; ++i) {
      const int oc = oc0 + i;
      const float inv = bng[oc] * rsqrtf(bnv[oc] + EPSBN);
      sc[i] = inv;
      float s0 = bnb[oc] - bnm[oc] * inv;
      if (bias) s0 += bias[oc] * inv;  // conv bias folded into BN shift
      sh2[i] = s0;
    }
    float yv[8][4];
    #pragma unroll
    for (int i = 0; i < 8; ++i) {
      #pragma unroll
      for (int j = 0; j < 4; ++j)
        yv[i][j] = fmaxf(fmaf(acc[i][j], sc[i], sh2[i]), 0.f);
    }

    if constexpr (EPI == 0) {
      #pragma unroll
      for (int j = 0; j < 4; ++j) {
        float* op = out + ((size_t)((b * 96 + oh) * 96 + ow0 + j)) * 64 + oc0;
        *(float4*)op = make_float4(yv[0][j], yv[1][j], yv[2][j], yv[3][j]);
        *(float4*)(op + 4) = make_float4(yv[4][j], yv[5][j], yv[6][j], yv[7][j]);
      }
    } else {  // EPI == 2: fused 1x1 conv + sigmoid
      __shared__ float red[128];
      float part[4];
      #pragma unroll
      for (int j = 0; j < 4; ++j) {
        float p = 0.f;
        #pragma unroll
        for (int i = 0; i < 8; ++i) p = fmaf(ow[oc0 + i], yv[i][j], p);
        part[j] = p;
      }
      if (t < 128) red[t] = 0.f;
      __syncthreads();
      #pragma unroll
      for (int j = 0; j < 4; ++j) atomicAdd(&red[pgrp * 4 + j], part[j]);
      __syncthreads();
      if (t < 128) {
        const int ly = t >> 4, lx = t & 15;
        const float v = red[t] + ob[0];
        out[((size_t)(b * 96 + y0 + ly)) * 96 + (x0 + lx)] =
            1.f / (1.f + expf(-v));
      }
    }
  }
}

// ---------------------------------------------------------------------------
// Deformable conv. Block: 16x8 px tile x 64 oc. Per k: bilinear-sample
// s[ic][px] into LDS, then 128px x 64oc x 64ic GEMM from LDS + global wt.
// Epilogue: BN2 + ReLU -> x2 NHWC64.
// ---------------------------------------------------------------------------
__global__ __launch_bounds__(256, 2) void deform_kernel(
    const float* __restrict__ x1, const float* __restrict__ off,
    const float* __restrict__ wkt,
    const float* __restrict__ bng, const float* __restrict__ bnb,
    const float* __restrict__ bnm, const float* __restrict__ bnv,
    float* __restrict__ out)
{
  __shared__ __align__(16) float s[64][128];  // [ic][px], 32 KB
  const int t = threadIdx.x;
  const int x0 = blockIdx.x * 16, y0 = blockIdx.y * 8;
  const int b = blockIdx.z;
  const int pgrp = t & 31, ocb = t >> 5, oc0 = ocb * 8;
  const int p = t & 127, half = t >> 7;  // staging role: pixel p, ic-half
  const int ly = p >> 4, lx = p & 15;
  const int h = y0 + ly, w = x0 + lx;
  const float* offp = off + ((size_t)((b * 96 + h) * 96 + w)) * 64;
  float acc[8][4] = {};

  for (int k = 0; k < 9; ++k) {
    __syncthreads();
    {  // staging: bilinear sample 32 channels for pixel p at kernel tap k
      const float oy = offp[2 * k];
      const float ox = offp[2 * k + 1];
      const float py = (float)(h + k / 3 - 1) + oy;
      const float px = (float)(w + k % 3 - 1) + ox;
      const float yf = floorf(py), xf = floorf(px);
      const float fy = py - yf, fx = px - xf;
      const int yi = (int)yf, xi = (int)xf;
      float4 sv[8];
      #pragma unroll
      for (int r = 0; r < 8; ++r) sv[r] = make_float4(0.f, 0.f, 0.f, 0.f);
      #pragma unroll
      for (int cor = 0; cor < 4; ++cor) {
        const int cy = yi + (cor >> 1), cx = xi + (cor & 1);
        if ((unsigned)cy < 96u && (unsigned)cx < 96u) {
          const float wy = (cor & 2) ? fy : 1.f - fy;
          const float wx = (cor & 1) ? fx : 1.f - fx;
          const float wgt = wy * wx;
          const float* sp =
              x1 + ((size_t)((b * 96 + cy) * 96 + cx)) * 64 + half * 32;
          #pragma unroll
          for (int r = 0; r < 8; ++r) {
            const float4 v = *(const float4*)(sp + r * 4);
            sv[r].x = fmaf(wgt, v.x, sv[r].x);
            sv[r].y = fmaf(wgt, v.y, sv[r].y);
            sv[r].z = fmaf(wgt, v.z, sv[r].z);
            sv[r].w = fmaf(wgt, v.w, sv[r].w);
          }
        }
      }
      #pragma unroll
      for (int r = 0; r < 8; ++r) {
        const int ic = half * 32 + r * 4;
        s[ic + 0][p] = sv[r].x;
        s[ic + 1][p] = sv[r].y;
        s[ic + 2][p] = sv[r].z;
        s[ic + 3][p] = sv[r].w;
      }
    }
    __syncthreads();
    // GEMM: acc[oc][px] += s[ic][px] * wk[oc][ic][k]
    const float* wkp = wkt + (size_t)k * 4096 + oc0;
    #pragma unroll 4
    for (int ic = 0; ic < 64; ++ic) {
      const float4 a = *(const float4*)&s[ic][pgrp * 4];
      const float4 w0 = *(const float4*)(wkp + ic * 64);
      const float4 w1 = *(const float4*)(wkp + ic * 64 + 4);
      const float w8[8] = {w0.x, w0.y, w0.z, w0.w, w1.x, w1.y, w1.z, w1.w};
      const float a4[4] = {a.x, a.y, a.z, a.w};
      #pragma unroll
      for (int i = 0; i < 8; ++i) {
        #pragma unroll
        for (int j = 0; j < 4; ++j)
          acc[i][j] = fmaf(w8[i], a4[j], acc[i][j]);
      }
    }
  }

  // epilogue: BN2 + ReLU
  float sc[8], sh2[8];
  #pragma unroll
  for (int i = 0; i < 8; ++i) {
    const int oc = oc0 + i;
    const float inv = bng[oc] * rsqrtf(bnv[oc] + EPSBN);
    sc[i] = inv;
    sh2[i] = bnb[oc] - bnm[oc] * inv;
  }
  #pragma unroll
  for (int j = 0; j < 4; ++j) {
    const int p2 = pgrp * 4 + j;
    const int oh = y0 + (p2 >> 4), owx = x0 + (p2 & 15);
    float yv[8];
    #pragma unroll
    for (int i = 0; i < 8; ++i)
      yv[i] = fmaxf(fmaf(acc[i][j], sc[i], sh2[i]), 0.f);
    float* op = out + ((size_t)((b * 96 + oh) * 96 + owx)) * 64 + oc0;
    *(float4*)op = make_float4(yv[0], yv[1], yv[2], yv[3]);
    *(float4*)(op + 4) = make_float4(yv[4], yv[5], yv[6], yv[7]);
  }
}

extern "C" void kernel_launch(void* const* d_in, const int* in_sizes, int n_in,
                              void* d_out, int out_size, void* d_ws,
                              size_t ws_size, hipStream_t stream)
{
  (void)in_sizes; (void)n_in; (void)out_size; (void)ws_size;
  const float* features = (const float*)d_in[0];
  const float* coord_w  = (const float*)d_in[1];
  const float* coord_b  = (const float*)d_in[2];
  const float* bn1g = (const float*)d_in[3];
  const float* bn1b = (const float*)d_in[4];
  const float* bn1m = (const float*)d_in[5];
  const float* bn1v = (const float*)d_in[6];
  const float* off_w = (const float*)d_in[7];
  const float* off_b = (const float*)d_in[8];
  const float* dc_w  = (const float*)d_in[9];
  const float* bn2g = (const float*)d_in[10];
  const float* bn2b = (const float*)d_in[11];
  const float* bn2m = (const float*)d_in[12];
  const float* bn2v = (const float*)d_in[13];
  const float* r1_w = (const float*)d_in[14];
  const float* bn3g = (const float*)d_in[15];
  const float* bn3b = (const float*)d_in[16];
  const float* bn3m = (const float*)d_in[17];
  const float* bn3v = (const float*)d_in[18];
  const float* r2_w = (const float*)d_in[19];
  const float* bn4g = (const float*)d_in[20];
  const float* bn4b = (const float*)d_in[21];
  const float* bn4m = (const float*)d_in[22];
  const float* bn4v = (const float*)d_in[23];
  const float* out_w = (const float*)d_in[24];
  const float* out_b = (const float*)d_in[25];

  float* ws  = (float*)d_ws;
  float* x1  = ws + X1_OFF;
  float* off = ws + OFF_OFF;
  float* x2  = ws + X2_OFF;
  float* x3  = x1;  // alias: x1 dead after deform
  const float* cwt  = ws + CWT_OFF;
  const float* owt  = ws + OWT_OFF;
  const float* r1wt = ws + R1WT_OFF;
  const float* r2wt = ws + R2WT_OFF;
  const float* dcwt = ws + DCWT_OFF;

  prep_weights<<<1170, 256, 0, stream>>>(coord_w, off_w, r1_w, r2_w, dc_w, ws);

  dim3 grid(6, 12, 8);  // 16x8 tiles over 96x96, 8 batches
  // coord conv + BN1 + ReLU -> x1
  conv3x3_kernel<264, 256, true, 0><<<grid, 256, 0, stream>>>(
      features, cwt, coord_b, bn1g, bn1b, bn1m, bn1v, nullptr, nullptr, x1);
  // offset conv (+bias) -> off (padded 64 ch)
  conv3x3_kernel<64, 64, false, 1><<<grid, 256, 0, stream>>>(
      x1, owt, off_b, nullptr, nullptr, nullptr, nullptr, nullptr, nullptr, off);
  // deform conv + BN2 + ReLU -> x2
  deform_kernel<<<grid, 256, 0, stream>>>(x1, off, dcwt, bn2g, bn2b, bn2m,
                                          bn2v, x2);
  // r1 conv + BN3 + ReLU -> x3
  conv3x3_kernel<64, 64, false, 0><<<grid, 256, 0, stream>>>(
      x2, r1wt, nullptr, bn3g, bn3b, bn3m, bn3v, nullptr, nullptr, x3);
  // r2 conv + BN4 + ReLU + 1x1 out conv + sigmoid -> d_out
  conv3x3_kernel<64, 64, false, 2><<<grid, 256, 0, stream>>>(
      x3, r2wt, nullptr, bn4g, bn4b, bn4m, bn4v, out_w, out_b, (float*)d_out);
}

// Round 2
// 280.655 us; speedup vs baseline: 4.0986x; 4.0986x over previous
//
#include <hip/hip_runtime.h>

// ---------------------------------------------------------------------------
// SpatialHead, bf16-MFMA version. All convs = implicit GEMM on
// mfma_f32_16x16x32_bf16 (A: 16px x K, B: K x 16oc). Activations NHWC bf16.
// Layout facts used (verified per guide §3): A[m=lane&15][k=(lane>>4)*8+j],
// B[n=lane&15][k=(lane>>4)*8+j], D col=lane&15, row=(lane>>4)*4+reg.
// LDS tiles pad channel stride to 72 (144 B = 36 dwords == 4 mod 32) ->
// bank-balanced b128 reads, 16B aligned.
// ---------------------------------------------------------------------------

typedef unsigned short u16;
typedef unsigned int u32;
typedef __attribute__((ext_vector_type(8))) short bf16x8;   // 8 bf16
typedef __attribute__((ext_vector_type(4))) float f32x4;

#define EPSBN 1e-5f

__device__ __forceinline__ u16 f2bf(float f) {          // RNE fp32->bf16
  u32 u = __builtin_bit_cast(u32, f);
  u32 r = u + 0x7FFFu + ((u >> 16) & 1u);
  return (u16)(r >> 16);
}
__device__ __forceinline__ float lo2f(u32 w) { return __builtin_bit_cast(float, w << 16); }
__device__ __forceinline__ float hi2f(u32 w) { return __builtin_bit_cast(float, w & 0xFFFF0000u); }

// ---------------------------------------------------------------------------
// ws layout (bytes):
//  0         x0b bf16 [8][96][96][256]          37,748,736
//    alias:  offb fp32 [8][96][96][18]           5,308,416  (after x0b dead)
//    alias:  x3b  bf16 at +8,388,608             9,437,184  (after x0b dead)
//  37748736  x1b bf16 [8][96][96][64]            9,437,184
//  47185920  x2b bf16                            9,437,184
//  56623104  weight frags (bf16) + coord-ch weights (fp32)
//  total ~57.2 MB (< round-0's 57.8 MB which fit)
// Frag layouts: w[tap][ick][octile][lane][8] where ic=ick*32+(lane>>4)*8+j,
// oc=octile*16+(lane&15).
// ---------------------------------------------------------------------------

#define SEG_X0   4718592   // x0b float4 items (x4 elements)
#define SEG_WCF  147456    // 9*8*4*512
#define SEG_WOF  18432     // 9*2*2*512
#define SEG_W64  36864     // 9*2*4*512
#define SEG_CXY  1152
#define SEG_TOT  (SEG_X0 + SEG_WCF + SEG_WOF + 3*SEG_W64 + SEG_CXY)

__global__ __launch_bounds__(256) void prep_kernel(
    const float* __restrict__ features, const float* __restrict__ coord_w,
    const float* __restrict__ off_w, const float* __restrict__ dc_w,
    const float* __restrict__ r1_w, const float* __restrict__ r2_w,
    u16* __restrict__ x0b, u16* __restrict__ wcf, u16* __restrict__ wof,
    u16* __restrict__ wdf, u16* __restrict__ wr1, u16* __restrict__ wr2,
    float* __restrict__ wcx, float* __restrict__ wcy)
{
  for (long long i = (long long)blockIdx.x * 256 + threadIdx.x; i < SEG_TOT;
       i += (long long)gridDim.x * 256) {
    long long d = i;
    if (d < SEG_X0) {
      float4 f = ((const float4*)features)[d];
      ushort4 u;
      u.x = f2bf(f.x); u.y = f2bf(f.y); u.z = f2bf(f.z); u.w = f2bf(f.w);
      ((ushort4*)x0b)[d] = u;
      continue;
    }
    d -= SEG_X0;
    if (d < SEG_WCF) {
      int j = d & 7, lane = (d >> 3) & 63, o = (d >> 9) & 3;
      int ick = (d >> 11) & 7, tap = (int)(d >> 14);
      int ic = ick * 32 + ((lane >> 4) << 3) + j;
      int oc = o * 16 + (lane & 15);
      wcf[d] = f2bf(coord_w[((size_t)oc * 258 + ic) * 9 + tap]);
      continue;
    }
    d -= SEG_WCF;
    if (d < SEG_WOF) {
      int j = d & 7, lane = (d >> 3) & 63, o = (d >> 9) & 1;
      int ick = (d >> 10) & 1, tap = (int)(d >> 11);
      int ic = ick * 32 + ((lane >> 4) << 3) + j;
      int oc = o * 16 + (lane & 15);
      wof[d] = (oc < 18) ? f2bf(off_w[((size_t)oc * 64 + ic) * 9 + tap]) : (u16)0;
      continue;
    }
    d -= SEG_WOF;
    if (d < 3 * SEG_W64) {
      int seg = (int)(d / SEG_W64);
      long long e = d - (long long)seg * SEG_W64;
      int j = e & 7, lane = (e >> 3) & 63, o = (e >> 9) & 3;
      int ick = (e >> 11) & 1, tap = (int)(e >> 12);
      int ic = ick * 32 + ((lane >> 4) << 3) + j;
      int oc = o * 16 + (lane & 15);
      const float* src = (seg == 0) ? dc_w : (seg == 1) ? r1_w : r2_w;
      u16* dst = (seg == 0) ? wdf : (seg == 1) ? wr1 : wr2;
      dst[e] = f2bf(src[((size_t)oc * 64 + ic) * 9 + tap]);
      continue;
    }
    d -= 3 * SEG_W64;
    // coord-channel weights, fp32: wcx/wcy[tap*64+oc]
    if (d < 576) {
      int tap = (int)(d >> 6), oc = (int)(d & 63);
      wcx[d] = coord_w[((size_t)oc * 258 + 256) * 9 + tap];
    } else {
      long long e = d - 576;
      int tap = (int)(e >> 6), oc = (int)(e & 63);
      wcy[e] = coord_w[((size_t)oc * 258 + 257) * 9 + tap];
    }
  }
}

// ---------------------------------------------------------------------------
// Coord conv: 256(+2 virtual) -> 64, BN1+ReLU -> x1b bf16.
// Block: 16x4 px tile, 4 waves. Wave: 2 Mtiles (rows) x 2 octiles (hybrid
// split -> balances LDS A-traffic vs L2 B-traffic). 4 ic-chunks of 64.
// Coord channels added analytically (fp32) in epilogue.
// ---------------------------------------------------------------------------
__global__ __launch_bounds__(256, 4) void coord_conv_kernel(
    const u16* __restrict__ x0b, const u16* __restrict__ wcf,
    const float* __restrict__ wcx, const float* __restrict__ wcy,
    const float* __restrict__ cb,
    const float* __restrict__ g, const float* __restrict__ bb,
    const float* __restrict__ m, const float* __restrict__ v,
    u16* __restrict__ x1b)
{
  __shared__ __align__(16) u16 tile[6 * 18 * 72];
  const int t = threadIdx.x;
  const int wv = t >> 6, lane = t & 63;
  const int col = lane & 15, quad = lane >> 4;
  const int o0 = (wv & 1) * 2, m0 = (wv >> 1) * 2;
  const int x0 = blockIdx.x * 16, y0 = blockIdx.y * 4, b = blockIdx.z;

  const f32x4 zf = {0.f, 0.f, 0.f, 0.f};
  f32x4 acc[2][2] = {{zf, zf}, {zf, zf}};

  for (int icc = 0; icc < 4; ++icc) {
    __syncthreads();
    for (int i = t; i < 864; i += 256) {
      const int px = i >> 3, part = i & 7;
      const int ly = px / 18, lx = px - ly * 18;
      const int gy = y0 + ly - 1, gx = x0 + lx - 1;
      uint4 val = {0u, 0u, 0u, 0u};
      if ((unsigned)gy < 96u && (unsigned)gx < 96u)
        val = *(const uint4*)(x0b + (((size_t)((b * 96 + gy) * 96 + gx)) << 8)
                              + icc * 64 + part * 8);
      *(uint4*)(tile + (ly * 18 + lx) * 72 + part * 8) = val;
    }
    __syncthreads();
    #pragma unroll
    for (int tap = 0; tap < 9; ++tap) {
      const int dy = tap / 3, dx = tap - dy * 3;
      #pragma unroll
      for (int half = 0; half < 2; ++half) {
        const int ick = icc * 2 + half;
        bf16x8 bfr[2], afr[2];
        #pragma unroll
        for (int ot = 0; ot < 2; ++ot)
          bfr[ot] = *(const bf16x8*)(wcf +
              ((size_t)((tap * 8 + ick) * 4 + o0 + ot)) * 512 + lane * 8);
        #pragma unroll
        for (int mt = 0; mt < 2; ++mt)
          afr[mt] = *(const bf16x8*)(tile +
              ((m0 + mt + dy) * 18 + col + dx) * 72 + half * 32 + quad * 8);
        #pragma unroll
        for (int mt = 0; mt < 2; ++mt)
          #pragma unroll
          for (int ot = 0; ot < 2; ++ot)
            acc[mt][ot] = __builtin_amdgcn_mfma_f32_16x16x32_bf16(
                afr[mt], bfr[ot], acc[mt][ot], 0, 0, 0);
      }
    }
  }

  #pragma unroll
  for (int ot = 0; ot < 2; ++ot) {
    const int oc = (o0 + ot) * 16 + col;
    const float inv = g[oc] * rsqrtf(v[oc] + EPSBN);
    const float sh = bb[oc] - m[oc] * inv + cb[oc] * inv;  // fold conv bias
    #pragma unroll
    for (int mt = 0; mt < 2; ++mt) {
      const int y = y0 + m0 + mt;
      #pragma unroll
      for (int r = 0; r < 4; ++r) {
        const int x = x0 + quad * 4 + r;
        float val = acc[mt][ot][r];
        #pragma unroll
        for (int tap = 0; tap < 9; ++tap) {
          const int sy = y + tap / 3 - 1, sx = x + tap % 3 - 1;
          if ((unsigned)sy < 96u && (unsigned)sx < 96u)
            val += wcx[tap * 64 + oc] * (-1.f + (2.f / 95.f) * (float)sx)
                 + wcy[tap * 64 + oc] * (-1.f + (2.f / 95.f) * (float)sy);
        }
        val = fmaxf(fmaf(val, inv, sh), 0.f);
        x1b[((size_t)((b * 96 + y) * 96 + x)) * 64 + oc] = f2bf(val);
      }
    }
  }
}

// ---------------------------------------------------------------------------
// Generic 64->64ch 3x3 conv (bf16 in NHWC64).
// EPI: 0 = BN+ReLU -> bf16 NHWC64 ; 1 = +bias -> fp32 NHWC18 (offset conv,
//      NOCT=2) ; 2 = BN+ReLU + 1x1 out conv + sigmoid -> fp32 (B,96,96)
// ---------------------------------------------------------------------------
template<int NOCT, int EPI>
__global__ __launch_bounds__(256, 4) void conv64_kernel(
    const u16* __restrict__ xin, const u16* __restrict__ wf,
    const float* __restrict__ bias,
    const float* __restrict__ g, const float* __restrict__ bb,
    const float* __restrict__ m, const float* __restrict__ v,
    const float* __restrict__ ow, const float* __restrict__ ob,
    void* __restrict__ outp)
{
  __shared__ __align__(16) u16 tile[6 * 18 * 72];
  __shared__ float red[64];
  const int t = threadIdx.x;
  const int wv = t >> 6, lane = t & 63;
  const int col = lane & 15, quad = lane >> 4;
  constexpr int OW = (NOCT == 4) ? 2 : 1;  // octiles per wave
  const int o0 = (NOCT == 4) ? (wv & 1) * 2 : (wv & 1);
  const int m0 = (wv >> 1) * 2;
  const int x0 = blockIdx.x * 16, y0 = blockIdx.y * 4, b = blockIdx.z;

  if constexpr (EPI == 2) { if (t < 64) red[t] = 0.f; }

  for (int i = t; i < 864; i += 256) {
    const int px = i >> 3, part = i & 7;
    const int ly = px / 18, lx = px - ly * 18;
    const int gy = y0 + ly - 1, gx = x0 + lx - 1;
    uint4 val = {0u, 0u, 0u, 0u};
    if ((unsigned)gy < 96u && (unsigned)gx < 96u)
      val = *(const uint4*)(xin + (((size_t)((b * 96 + gy) * 96 + gx)) << 6)
                            + part * 8);
    *(uint4*)(tile + (ly * 18 + lx) * 72 + part * 8) = val;
  }
  __syncthreads();

  const f32x4 zf = {0.f, 0.f, 0.f, 0.f};
  f32x4 acc[2][OW];
  #pragma unroll
  for (int a = 0; a < 2; ++a)
    #pragma unroll
    for (int o = 0; o < OW; ++o) acc[a][o] = zf;

  #pragma unroll
  for (int tap = 0; tap < 9; ++tap) {
    const int dy = tap / 3, dx = tap - dy * 3;
    #pragma unroll
    for (int half = 0; half < 2; ++half) {
      bf16x8 bfr[OW], afr[2];
      #pragma unroll
      for (int ot = 0; ot < OW; ++ot)
        bfr[ot] = *(const bf16x8*)(wf +
            ((size_t)((tap * 2 + half) * NOCT + o0 + ot)) * 512 + lane * 8);
      #pragma unroll
      for (int mt = 0; mt < 2; ++mt)
        afr[mt] = *(const bf16x8*)(tile +
            ((m0 + mt + dy) * 18 + col + dx) * 72 + half * 32 + quad * 8);
      #pragma unroll
      for (int mt = 0; mt < 2; ++mt)
        #pragma unroll
        for (int ot = 0; ot < OW; ++ot)
          acc[mt][ot] = __builtin_amdgcn_mfma_f32_16x16x32_bf16(
              afr[mt], bfr[ot], acc[mt][ot], 0, 0, 0);
    }
  }

  if constexpr (EPI == 0) {
    u16* xo = (u16*)outp;
    #pragma unroll
    for (int ot = 0; ot < OW; ++ot) {
      const int oc = (o0 + ot) * 16 + col;
      const float inv = g[oc] * rsqrtf(v[oc] + EPSBN);
      const float sh = bb[oc] - m[oc] * inv;
      #pragma unroll
      for (int mt = 0; mt < 2; ++mt) {
        const int y = y0 + m0 + mt;
        #pragma unroll
        for (int r = 0; r < 4; ++r) {
          const int x = x0 + quad * 4 + r;
          const float val = fmaxf(fmaf(acc[mt][ot][r], inv, sh), 0.f);
          xo[((size_t)((b * 96 + y) * 96 + x)) * 64 + oc] = f2bf(val);
        }
      }
    }
  } else if constexpr (EPI == 1) {
    float* fo = (float*)outp;
    const int oc = o0 * 16 + col;
    if (oc < 18) {
      const float bs = bias[oc];
      #pragma unroll
      for (int mt = 0; mt < 2; ++mt) {
        const int y = y0 + m0 + mt;
        #pragma unroll
        for (int r = 0; r < 4; ++r) {
          const int x = x0 + quad * 4 + r;
          fo[((size_t)((b * 96 + y) * 96 + x)) * 18 + oc] = acc[mt][0][r] + bs;
        }
      }
    }
  } else {  // EPI == 2: BN+ReLU, 1x1 conv, sigmoid
    float pr[2][4];
    #pragma unroll
    for (int mt = 0; mt < 2; ++mt)
      #pragma unroll
      for (int r = 0; r < 4; ++r) pr[mt][r] = 0.f;
    #pragma unroll
    for (int ot = 0; ot < OW; ++ot) {
      const int oc = (o0 + ot) * 16 + col;
      const float inv = g[oc] * rsqrtf(v[oc] + EPSBN);
      const float sh = bb[oc] - m[oc] * inv;
      const float wo = ow[oc];
      #pragma unroll
      for (int mt = 0; mt < 2; ++mt)
        #pragma unroll
        for (int r = 0; r < 4; ++r) {
          const float val = fmaxf(fmaf(acc[mt][ot][r], inv, sh), 0.f);
          pr[mt][r] = fmaf(val, wo, pr[mt][r]);
        }
    }
    #pragma unroll
    for (int mask = 1; mask <= 8; mask <<= 1)
      #pragma unroll
      for (int mt = 0; mt < 2; ++mt)
        #pragma unroll
        for (int r = 0; r < 4; ++r)
          pr[mt][r] += __shfl_xor(pr[mt][r], mask);
    if (col == 0) {
      #pragma unroll
      for (int mt = 0; mt < 2; ++mt)
        #pragma unroll
        for (int r = 0; r < 4; ++r)
          atomicAdd(&red[(m0 + mt) * 16 + quad * 4 + r], pr[mt][r]);
    }
    __syncthreads();
    if (t < 64) {
      float* fo = (float*)outp;
      const int y = y0 + (t >> 4), x = x0 + (t & 15);
      const float val = red[t] + ob[0];
      fo[(size_t)(b * 96 + y) * 96 + x] = 1.f / (1.f + expf(-val));
    }
  }
}

// ---------------------------------------------------------------------------
// Deformable conv. Per tap k: bilinear-sample 64px x 64ch (fp32 math) into
// bf16 LDS tile, then MFMA (hybrid 2x2 split). BN2+ReLU -> x2b.
// ---------------------------------------------------------------------------
__global__ __launch_bounds__(256, 4) void deform_kernel(
    const u16* __restrict__ x1b, const float* __restrict__ off,
    const u16* __restrict__ wdf,
    const float* __restrict__ g, const float* __restrict__ bb,
    const float* __restrict__ m, const float* __restrict__ v,
    u16* __restrict__ x2b)
{
  __shared__ __align__(16) u16 s[64 * 72];
  __shared__ float offs[64 * 18];
  const int t = threadIdx.x;
  const int wv = t >> 6, lane = t & 63;
  const int col = lane & 15, quad = lane >> 4;
  const int o0 = (wv & 1) * 2, m0 = (wv >> 1) * 2;
  const int x0 = blockIdx.x * 16, y0 = blockIdx.y * 4, b = blockIdx.z;

  for (int i = t; i < 64 * 18; i += 256) {
    const int p = i / 18, c = i - p * 18;
    const int gy = y0 + (p >> 4), gx = x0 + (p & 15);
    offs[i] = off[((size_t)((b * 96 + gy) * 96 + gx)) * 18 + c];
  }

  const int sp_px = t >> 2, sp_part = t & 3;  // staging: pixel, 16-ch group
  const int sh_y = y0 + (sp_px >> 4), sh_x = x0 + (sp_px & 15);

  const f32x4 zf = {0.f, 0.f, 0.f, 0.f};
  f32x4 acc[2][2] = {{zf, zf}, {zf, zf}};

  for (int k = 0; k < 9; ++k) {
    __syncthreads();
    {
      const float oy = offs[sp_px * 18 + 2 * k];
      const float ox = offs[sp_px * 18 + 2 * k + 1];
      const float py = (float)(sh_y + k / 3 - 1) + oy;
      const float px = (float)(sh_x + k % 3 - 1) + ox;
      const float yf = floorf(py), xf = floorf(px);
      const float fy = py - yf, fx = px - xf;
      const int yi = (int)yf, xi = (int)xf;
      float val[16];
      #pragma unroll
      for (int j = 0; j < 16; ++j) val[j] = 0.f;
      #pragma unroll
      for (int c4 = 0; c4 < 4; ++c4) {
        const int cy = yi + (c4 >> 1), cx = xi + (c4 & 1);
        if ((unsigned)cy < 96u && (unsigned)cx < 96u) {
          const float wy = (c4 & 2) ? fy : 1.f - fy;
          const float wx = (c4 & 1) ? fx : 1.f - fx;
          const float wgt = wy * wx;
          const u16* spn = x1b + ((size_t)((b * 96 + cy) * 96 + cx)) * 64
                           + sp_part * 16;
          const uint4 ua = *(const uint4*)spn;
          const uint4 ub = *(const uint4*)(spn + 8);
          const u32 uu[8] = {ua.x, ua.y, ua.z, ua.w, ub.x, ub.y, ub.z, ub.w};
          #pragma unroll
          for (int u = 0; u < 8; ++u) {
            val[2 * u]     = fmaf(wgt, lo2f(uu[u]), val[2 * u]);
            val[2 * u + 1] = fmaf(wgt, hi2f(uu[u]), val[2 * u + 1]);
          }
        }
      }
      u32 pk[8];
      #pragma unroll
      for (int u = 0; u < 8; ++u)
        pk[u] = (u32)f2bf(val[2 * u]) | ((u32)f2bf(val[2 * u + 1]) << 16);
      uint4 w0 = {pk[0], pk[1], pk[2], pk[3]};
      uint4 w1 = {pk[4], pk[5], pk[6], pk[7]};
      *(uint4*)(s + sp_px * 72 + sp_part * 16) = w0;
      *(uint4*)(s + sp_px * 72 + sp_part * 16 + 8) = w1;
    }
    __syncthreads();
    #pragma unroll
    for (int half = 0; half < 2; ++half) {
      bf16x8 bfr[2], afr[2];
      #pragma unroll
      for (int ot = 0; ot < 2; ++ot)
        bfr[ot] = *(const bf16x8*)(wdf +
            ((size_t)((k * 2 + half) * 4 + o0 + ot)) * 512 + lane * 8);
      #pragma unroll
      for (int mt = 0; mt < 2; ++mt)
        afr[mt] = *(const bf16x8*)(s + ((m0 + mt) * 16 + col) * 72
                                   + half * 32 + quad * 8);
      #pragma unroll
      for (int mt = 0; mt < 2; ++mt)
        #pragma unroll
        for (int ot = 0; ot < 2; ++ot)
          acc[mt][ot] = __builtin_amdgcn_mfma_f32_16x16x32_bf16(
              afr[mt], bfr[ot], acc[mt][ot], 0, 0, 0);
    }
  }

  #pragma unroll
  for (int ot = 0; ot < 2; ++ot) {
    const int oc = (o0 + ot) * 16 + col;
    const float inv = g[oc] * rsqrtf(v[oc] + EPSBN);
    const float sh = bb[oc] - m[oc] * inv;
    #pragma unroll
    for (int mt = 0; mt < 2; ++mt) {
      const int y = y0 + m0 + mt;
      #pragma unroll
      for (int r = 0; r < 4; ++r) {
        const int x = x0 + quad * 4 + r;
        const float val = fmaxf(fmaf(acc[mt][ot][r], inv, sh), 0.f);
        x2b[((size_t)((b * 96 + y) * 96 + x)) * 64 + oc] = f2bf(val);
      }
    }
  }
}

extern "C" void kernel_launch(void* const* d_in, const int* in_sizes, int n_in,
                              void* d_out, int out_size, void* d_ws,
                              size_t ws_size, hipStream_t stream)
{
  (void)in_sizes; (void)n_in; (void)out_size; (void)ws_size;
  const float* features = (const float*)d_in[0];
  const float* coord_w  = (const float*)d_in[1];
  const float* coord_b  = (const float*)d_in[2];
  const float* bn1g = (const float*)d_in[3];
  const float* bn1b = (const float*)d_in[4];
  const float* bn1m = (const float*)d_in[5];
  const float* bn1v = (const float*)d_in[6];
  const float* off_w = (const float*)d_in[7];
  const float* off_b = (const float*)d_in[8];
  const float* dc_w  = (const float*)d_in[9];
  const float* bn2g = (const float*)d_in[10];
  const float* bn2b = (const float*)d_in[11];
  const float* bn2m = (const float*)d_in[12];
  const float* bn2v = (const float*)d_in[13];
  const float* r1_w = (const float*)d_in[14];
  const float* bn3g = (const float*)d_in[15];
  const float* bn3b = (const float*)d_in[16];
  const float* bn3m = (const float*)d_in[17];
  const float* bn3v = (const float*)d_in[18];
  const float* r2_w = (const float*)d_in[19];
  const float* bn4g = (const float*)d_in[20];
  const float* bn4b = (const float*)d_in[21];
  const float* bn4m = (const float*)d_in[22];
  const float* bn4v = (const float*)d_in[23];
  const float* out_w = (const float*)d_in[24];
  const float* out_b = (const float*)d_in[25];

  char* W = (char*)d_ws;
  u16*   x0b  = (u16*)W;                       // dead after coord conv
  float* offb = (float*)W;                     // alias (written after x0b dead)
  u16*   x3b  = (u16*)(W + 8388608);           // alias in x0b region
  u16*   x1b  = (u16*)(W + 37748736);
  u16*   x2b  = (u16*)(W + 47185920);
  u16*   wcf  = (u16*)(W + 56623104);
  u16*   wof  = wcf + SEG_WCF;
  u16*   wdf  = wof + SEG_WOF;
  u16*   wr1  = wdf + SEG_W64;
  u16*   wr2  = wr1 + SEG_W64;
  float* wcx  = (float*)(W + 56623104 +
                         2 * (SEG_WCF + SEG_WOF + 3 * SEG_W64));
  float* wcy  = wcx + 576;

  prep_kernel<<<2048, 256, 0, stream>>>(features, coord_w, off_w, dc_w, r1_w,
                                        r2_w, x0b, wcf, wof, wdf, wr1, wr2,
                                        wcx, wcy);

  dim3 grid(6, 24, 8);  // 16x4 tiles over 96x96, 8 batches
  coord_conv_kernel<<<grid, 256, 0, stream>>>(
      x0b, wcf, wcx, wcy, coord_b, bn1g, bn1b, bn1m, bn1v, x1b);
  conv64_kernel<2, 1><<<grid, 256, 0, stream>>>(
      x1b, wof, off_b, nullptr, nullptr, nullptr, nullptr, nullptr, nullptr,
      (void*)offb);
  deform_kernel<<<grid, 256, 0, stream>>>(
      x1b, offb, wdf, bn2g, bn2b, bn2m, bn2v, x2b);
  conv64_kernel<4, 0><<<grid, 256, 0, stream>>>(
      x2b, wr1, nullptr, bn3g, bn3b, bn3m, bn3v, nullptr, nullptr, (void*)x3b);
  conv64_kernel<4, 2><<<grid, 256, 0, stream>>>(
      x3b, wr2, nullptr, bn4g, bn4b, bn4m, bn4v, out_w, out_b, d_out);
}

// Round 3
// 270.829 us; speedup vs baseline: 4.2473x; 1.0363x over previous
//
#include <hip/hip_runtime.h>

// ---------------------------------------------------------------------------
// SpatialHead, round 2: 32x32x16 bf16 MFMA everywhere, single-shot LDS
// staging, coord channels folded into an extra K-step, fp32 features read
// directly (no x0 conversion pass).
// MFMA 32x32x16_bf16 layouts: A[m=lane&31][k=(lane>>5)*8+j] (4 VGPR),
// B[n=lane&31][k=(lane>>5)*8+j], D col(lane&31)=n=oc,
// row m=(reg&3)+8*(reg>>2)+4*(lane>>5).  LDS px stride = 72 u16 (144 B,
// 36 dw == 4 mod 32, odd multiple of 4 -> conflict-free b128).
// ---------------------------------------------------------------------------

typedef unsigned short u16;
typedef unsigned int u32;
typedef __attribute__((ext_vector_type(8)))  short bf16x8;
typedef __attribute__((ext_vector_type(16))) float f32x16;

#define EPSBN 1e-5f

__device__ __forceinline__ u16 f2bf(float f) {          // RNE fp32->bf16
  u32 u = __builtin_bit_cast(u32, f);
  u32 r = u + 0x7FFFu + ((u >> 16) & 1u);
  return (u16)(r >> 16);
}
__device__ __forceinline__ u32 pk2(float a, float b) {
  return (u32)f2bf(a) | ((u32)f2bf(b) << 16);
}
__device__ __forceinline__ float lo2f(u32 w) { return __builtin_bit_cast(float, w << 16); }
__device__ __forceinline__ float hi2f(u32 w) { return __builtin_bit_cast(float, w & 0xFFFF0000u); }

// ---------------------------------------------------------------------------
// Weight fragment counts (u16):
//  wcf: [cc4][tap9][h4][nt2]*512        = 147456
//  wcc: [tap9][nt2]*512                 = 9216    (coord xx/yy channels)
//  wof: [tap9][h4]*512                  = 18432   (oc padded 18->32, nt=0)
//  wdf/wr1/wr2: [tap9][h4][nt2]*512     = 36864 each
// ---------------------------------------------------------------------------
#define N_WCF 147456
#define N_WCC 9216
#define N_WOF 18432
#define N_W64 36864
#define N_ALLW (N_WCF + N_WCC + N_WOF + 3*N_W64)   // 285696

__global__ __launch_bounds__(256) void prep_kernel(
    const float* __restrict__ coord_w, const float* __restrict__ off_w,
    const float* __restrict__ dc_w, const float* __restrict__ r1_w,
    const float* __restrict__ r2_w,
    u16* __restrict__ wcf, u16* __restrict__ wcc, u16* __restrict__ wof,
    u16* __restrict__ wdf, u16* __restrict__ wr1, u16* __restrict__ wr2)
{
  int i = blockIdx.x * 256 + threadIdx.x;
  if (i >= N_ALLW) return;
  int d = i;
  if (d < N_WCF) {
    int j = d & 7, lane = (d >> 3) & 63, frag = d >> 9;
    int nt = frag & 1, h = (frag >> 1) & 3, tap = (frag >> 3) % 9, cc = (frag >> 3) / 9;
    int ic = cc * 64 + h * 16 + ((lane >> 5) << 3) + j;
    int oc = nt * 32 + (lane & 31);
    wcf[d] = f2bf(coord_w[((size_t)oc * 258 + ic) * 9 + tap]);
    return;
  }
  d -= N_WCF;
  if (d < N_WCC) {
    int j = d & 7, lane = (d >> 3) & 63, frag = d >> 9;
    int nt = frag & 1, tap = frag >> 1;
    int ic = 256 + ((lane >> 5) << 3) + j;
    int oc = nt * 32 + (lane & 31);
    wcc[d] = (ic < 258) ? f2bf(coord_w[((size_t)oc * 258 + ic) * 9 + tap]) : (u16)0;
    return;
  }
  d -= N_WCC;
  if (d < N_WOF) {
    int j = d & 7, lane = (d >> 3) & 63, frag = d >> 9;
    int h = frag & 3, tap = frag >> 2;
    int ic = h * 16 + ((lane >> 5) << 3) + j;
    int oc = lane & 31;
    wof[d] = (oc < 18) ? f2bf(off_w[((size_t)oc * 64 + ic) * 9 + tap]) : (u16)0;
    return;
  }
  d -= N_WOF;
  int seg = d / N_W64;
  int e = d - seg * N_W64;
  int j = e & 7, lane = (e >> 3) & 63, frag = e >> 9;
  int nt = frag & 1, h = (frag >> 1) & 3, tap = frag >> 3;
  int ic = h * 16 + ((lane >> 5) << 3) + j;
  int oc = nt * 32 + (lane & 31);
  const float* src = (seg == 0) ? dc_w : (seg == 1) ? r1_w : r2_w;
  u16* dst = (seg == 0) ? wdf : (seg == 1) ? wr1 : wr2;
  dst[e] = f2bf(src[((size_t)oc * 64 + ic) * 9 + tap]);
}

// ---------------------------------------------------------------------------
// Coord conv 258->64 + BN1 + ReLU -> x1b (bf16 NHWC64).
// Block: 32x4 px tile (M=32 along x), 4 waves = 4 rows, 2 N-tiles each.
// fp32 features staged+converted per 64-ch chunk; coords = 1 extra K-step.
// ---------------------------------------------------------------------------
__global__ __launch_bounds__(256, 4) void coord_conv_kernel(
    const float* __restrict__ feat, const u16* __restrict__ wcf,
    const u16* __restrict__ wcc, const float* __restrict__ cb,
    const float* __restrict__ g, const float* __restrict__ bb,
    const float* __restrict__ m, const float* __restrict__ v,
    u16* __restrict__ x1b)
{
  __shared__ __align__(16) u16 tile[6 * 34 * 72];  // 29376 B
  const int t = threadIdx.x;
  const int wv = t >> 6, lane = t & 63;
  const int l31 = lane & 31, l5 = lane >> 5;
  const int x0 = blockIdx.x * 32, y0 = blockIdx.y * 4, b = blockIdx.z;

  f32x16 acc[2] = {};

  for (int cc = 0; cc < 4; ++cc) {
    __syncthreads();
    for (int i = t; i < 1632; i += 256) {
      const int px = i >> 3, gg = i & 7;
      const int ly = px / 34, lx = px - ly * 34;
      const int gy = y0 + ly - 1, gx = x0 + lx - 1;
      uint4 o = {0u, 0u, 0u, 0u};
      if ((unsigned)gy < 96u && (unsigned)gx < 96u) {
        const float* p = feat + ((size_t)((b * 96 + gy) * 96 + gx)) * 256
                         + cc * 64 + gg * 8;
        const float4 f0 = *(const float4*)p;
        const float4 f1 = *(const float4*)(p + 4);
        o.x = pk2(f0.x, f0.y); o.y = pk2(f0.z, f0.w);
        o.z = pk2(f1.x, f1.y); o.w = pk2(f1.z, f1.w);
      }
      *(uint4*)(tile + (ly * 34 + lx) * 72 + gg * 8) = o;
    }
    __syncthreads();
    #pragma unroll
    for (int tap = 0; tap < 9; ++tap) {
      const int dy = tap / 3, dx = tap - dy * 3;
      #pragma unroll
      for (int h = 0; h < 4; ++h) {
        const bf16x8 afr = *(const bf16x8*)(tile +
            ((wv + dy) * 34 + l31 + dx) * 72 + h * 16 + l5 * 8);
        #pragma unroll
        for (int nt = 0; nt < 2; ++nt) {
          const bf16x8 bfr = *(const bf16x8*)(wcf +
              ((size_t)((((cc * 9 + tap) * 4 + h) * 2) + nt)) * 512 + lane * 8);
          acc[nt] = __builtin_amdgcn_mfma_f32_32x32x16_bf16(afr, bfr, acc[nt],
                                                            0, 0, 0);
        }
      }
    }
  }

  // coordinate channels: one K=16 step (ch0=xx, ch1=yy, rest 0)
  __syncthreads();
  for (int i = t; i < 408; i += 256) {
    const int px = i >> 1, gg = i & 1;
    const int ly = px / 34, lx = px - ly * 34;
    const int gy = y0 + ly - 1, gx = x0 + lx - 1;
    uint4 o = {0u, 0u, 0u, 0u};
    if (gg == 0 && (unsigned)gy < 96u && (unsigned)gx < 96u) {
      const float xx = -1.f + (2.f / 95.f) * (float)gx;
      const float yy = -1.f + (2.f / 95.f) * (float)gy;
      o.x = pk2(xx, yy);
    }
    *(uint4*)(tile + (ly * 34 + lx) * 72 + gg * 8) = o;
  }
  __syncthreads();
  #pragma unroll
  for (int tap = 0; tap < 9; ++tap) {
    const int dy = tap / 3, dx = tap - dy * 3;
    const bf16x8 afr = *(const bf16x8*)(tile +
        ((wv + dy) * 34 + l31 + dx) * 72 + l5 * 8);
    #pragma unroll
    for (int nt = 0; nt < 2; ++nt) {
      const bf16x8 bfr = *(const bf16x8*)(wcc +
          ((size_t)(tap * 2 + nt)) * 512 + lane * 8);
      acc[nt] = __builtin_amdgcn_mfma_f32_32x32x16_bf16(afr, bfr, acc[nt],
                                                        0, 0, 0);
    }
  }

  // epilogue: BN1 (+conv bias) + ReLU -> bf16
  const int y = y0 + wv;
  #pragma unroll
  for (int nt = 0; nt < 2; ++nt) {
    const int oc = nt * 32 + l31;
    const float inv = g[oc] * rsqrtf(v[oc] + EPSBN);
    const float sh = bb[oc] - m[oc] * inv + cb[oc] * inv;
    #pragma unroll
    for (int r = 0; r < 16; ++r) {
      const int xr = (r & 3) + 8 * (r >> 2) + 4 * l5;
      const float val = fmaxf(fmaf(acc[nt][r], inv, sh), 0.f);
      x1b[((size_t)((b * 96 + y) * 96 + x0 + xr)) * 64 + oc] = f2bf(val);
    }
  }
}

// ---------------------------------------------------------------------------
// 64->64ch 3x3 conv (bf16 NHWC64 in). Block 32x4 px, 4 waves = rows.
// NN = N-tiles per wave (1: offset conv, 2: full 64 oc).
// EPI: 0 = BN+ReLU -> bf16 NHWC64 ; 1 = +bias -> fp32 NHWC18 (offset) ;
//      2 = BN+ReLU + 1x1 out conv + sigmoid -> fp32 (B,96,96)
// ---------------------------------------------------------------------------
template<int NN, int EPI>
__global__ __launch_bounds__(256, 4) void conv64_kernel(
    const u16* __restrict__ xin, const u16* __restrict__ wf,
    const float* __restrict__ bias,
    const float* __restrict__ g, const float* __restrict__ bb,
    const float* __restrict__ m, const float* __restrict__ v,
    const float* __restrict__ ow, const float* __restrict__ ob,
    void* __restrict__ outp)
{
  __shared__ __align__(16) u16 tile[6 * 34 * 72];
  __shared__ float red[128];
  const int t = threadIdx.x;
  const int wv = t >> 6, lane = t & 63;
  const int l31 = lane & 31, l5 = lane >> 5;
  const int x0 = blockIdx.x * 32, y0 = blockIdx.y * 4, b = blockIdx.z;

  for (int i = t; i < 1632; i += 256) {
    const int px = i >> 3, gg = i & 7;
    const int ly = px / 34, lx = px - ly * 34;
    const int gy = y0 + ly - 1, gx = x0 + lx - 1;
    uint4 o = {0u, 0u, 0u, 0u};
    if ((unsigned)gy < 96u && (unsigned)gx < 96u)
      o = *(const uint4*)(xin + (((size_t)((b * 96 + gy) * 96 + gx)) << 6)
                          + gg * 8);
    *(uint4*)(tile + (ly * 34 + lx) * 72 + gg * 8) = o;
  }
  __syncthreads();

  f32x16 acc[NN] = {};
  #pragma unroll
  for (int tap = 0; tap < 9; ++tap) {
    const int dy = tap / 3, dx = tap - dy * 3;
    #pragma unroll
    for (int h = 0; h < 4; ++h) {
      const bf16x8 afr = *(const bf16x8*)(tile +
          ((wv + dy) * 34 + l31 + dx) * 72 + h * 16 + l5 * 8);
      #pragma unroll
      for (int nt = 0; nt < NN; ++nt) {
        const bf16x8 bfr = *(const bf16x8*)(wf +
            ((size_t)((tap * 4 + h) * NN + nt)) * 512 + lane * 8);
        acc[nt] = __builtin_amdgcn_mfma_f32_32x32x16_bf16(afr, bfr, acc[nt],
                                                          0, 0, 0);
      }
    }
  }

  const int y = y0 + wv;
  if constexpr (EPI == 0) {
    u16* xo = (u16*)outp;
    #pragma unroll
    for (int nt = 0; nt < NN; ++nt) {
      const int oc = nt * 32 + l31;
      const float inv = g[oc] * rsqrtf(v[oc] + EPSBN);
      const float sh = bb[oc] - m[oc] * inv;
      #pragma unroll
      for (int r = 0; r < 16; ++r) {
        const int xr = (r & 3) + 8 * (r >> 2) + 4 * l5;
        const float val = fmaxf(fmaf(acc[nt][r], inv, sh), 0.f);
        xo[((size_t)((b * 96 + y) * 96 + x0 + xr)) * 64 + oc] = f2bf(val);
      }
    }
  } else if constexpr (EPI == 1) {
    float* fo = (float*)outp;
    const int oc = l31;
    if (oc < 18) {
      const float bs = bias[oc];
      #pragma unroll
      for (int r = 0; r < 16; ++r) {
        const int xr = (r & 3) + 8 * (r >> 2) + 4 * l5;
        fo[((size_t)((b * 96 + y) * 96 + x0 + xr)) * 18 + oc] = acc[0][r] + bs;
      }
    }
  } else {  // EPI == 2
    float pr[16];
    #pragma unroll
    for (int r = 0; r < 16; ++r) pr[r] = 0.f;
    #pragma unroll
    for (int nt = 0; nt < NN; ++nt) {
      const int oc = nt * 32 + l31;
      const float inv = g[oc] * rsqrtf(v[oc] + EPSBN);
      const float sh = bb[oc] - m[oc] * inv;
      const float wo = ow[oc];
      #pragma unroll
      for (int r = 0; r < 16; ++r) {
        const float val = fmaxf(fmaf(acc[nt][r], inv, sh), 0.f);
        pr[r] = fmaf(val, wo, pr[r]);
      }
    }
    #pragma unroll
    for (int mask = 1; mask <= 16; mask <<= 1)
      #pragma unroll
      for (int r = 0; r < 16; ++r)
        pr[r] += __shfl_xor(pr[r], mask);
    if (l31 == 0) {
      #pragma unroll
      for (int r = 0; r < 16; ++r) {
        const int xr = (r & 3) + 8 * (r >> 2) + 4 * l5;
        red[wv * 32 + xr] = pr[r];
      }
    }
    __syncthreads();
    if (t < 128) {
      float* fo = (float*)outp;
      const int yy = y0 + (t >> 5), xx = x0 + (t & 31);
      const float val = red[t] + ob[0];
      fo[(size_t)(b * 96 + yy) * 96 + xx] = 1.f / (1.f + expf(-val));
    }
  }
}

// ---------------------------------------------------------------------------
// Deformable conv 64->64 + BN2 + ReLU -> x2b. Block 16x8 px (128), 4 waves
// = 4 M-tiles of 32 px. Per tap: bilinear sample -> bf16 LDS, 4 K-steps.
// ---------------------------------------------------------------------------
__global__ __launch_bounds__(256, 4) void deform_kernel(
    const u16* __restrict__ x1b, const float* __restrict__ off,
    const u16* __restrict__ wdf,
    const float* __restrict__ g, const float* __restrict__ bb,
    const float* __restrict__ m, const float* __restrict__ v,
    u16* __restrict__ x2b)
{
  __shared__ __align__(16) u16 s[128 * 72];   // 18432 B
  __shared__ float offs[128 * 18];            // 9216 B
  const int t = threadIdx.x;
  const int wv = t >> 6, lane = t & 63;
  const int l31 = lane & 31, l5 = lane >> 5;
  const int x0 = blockIdx.x * 16, y0 = blockIdx.y * 8, b = blockIdx.z;

  for (int i = t; i < 2304; i += 256) {
    const int p = i / 18, c = i - p * 18;
    const int gy = y0 + (p >> 4), gx = x0 + (p & 15);
    offs[i] = off[((size_t)((b * 96 + gy) * 96 + gx)) * 18 + c];
  }

  f32x16 acc[2] = {};

  for (int k = 0; k < 9; ++k) {
    __syncthreads();
    #pragma unroll
    for (int rr = 0; rr < 2; ++rr) {  // 512 roles / 256 threads
      const int role = t + rr * 256;
      const int sp = role >> 2, part = role & 3;   // pixel, 16-ch group
      const int sy = y0 + (sp >> 4), sx = x0 + (sp & 15);
      const float oy = offs[sp * 18 + 2 * k];
      const float ox = offs[sp * 18 + 2 * k + 1];
      const float py = (float)(sy + k / 3 - 1) + oy;
      const float px = (float)(sx + k % 3 - 1) + ox;
      const float yf = floorf(py), xf = floorf(px);
      const float fy = py - yf, fx = px - xf;
      const int yi = (int)yf, xi = (int)xf;
      float val[16];
      #pragma unroll
      for (int j = 0; j < 16; ++j) val[j] = 0.f;
      #pragma unroll
      for (int cor = 0; cor < 4; ++cor) {
        const int cy = yi + (cor >> 1), cx = xi + (cor & 1);
        if ((unsigned)cy < 96u && (unsigned)cx < 96u) {
          const float wy = (cor & 2) ? fy : 1.f - fy;
          const float wx = (cor & 1) ? fx : 1.f - fx;
          const float wgt = wy * wx;
          const u16* sp2 = x1b + ((size_t)((b * 96 + cy) * 96 + cx)) * 64
                           + part * 16;
          const uint4 ua = *(const uint4*)sp2;
          const uint4 ub = *(const uint4*)(sp2 + 8);
          const u32 uu[8] = {ua.x, ua.y, ua.z, ua.w, ub.x, ub.y, ub.z, ub.w};
          #pragma unroll
          for (int u = 0; u < 8; ++u) {
            val[2 * u]     = fmaf(wgt, lo2f(uu[u]), val[2 * u]);
            val[2 * u + 1] = fmaf(wgt, hi2f(uu[u]), val[2 * u + 1]);
          }
        }
      }
      u32 pk[8];
      #pragma unroll
      for (int u = 0; u < 8; ++u) pk[u] = pk2(val[2 * u], val[2 * u + 1]);
      uint4 w0 = {pk[0], pk[1], pk[2], pk[3]};
      uint4 w1 = {pk[4], pk[5], pk[6], pk[7]};
      *(uint4*)(s + sp * 72 + part * 16) = w0;
      *(uint4*)(s + sp * 72 + part * 16 + 8) = w1;
    }
    __syncthreads();
    #pragma unroll
    for (int h = 0; h < 4; ++h) {
      const bf16x8 afr = *(const bf16x8*)(s + (wv * 32 + l31) * 72
                                          + h * 16 + l5 * 8);
      #pragma unroll
      for (int nt = 0; nt < 2; ++nt) {
        const bf16x8 bfr = *(const bf16x8*)(wdf +
            ((size_t)((k * 4 + h) * 2 + nt)) * 512 + lane * 8);
        acc[nt] = __builtin_amdgcn_mfma_f32_32x32x16_bf16(afr, bfr, acc[nt],
                                                          0, 0, 0);
      }
    }
  }

  #pragma unroll
  for (int nt = 0; nt < 2; ++nt) {
    const int oc = nt * 32 + l31;
    const float inv = g[oc] * rsqrtf(v[oc] + EPSBN);
    const float sh = bb[oc] - m[oc] * inv;
    #pragma unroll
    for (int r = 0; r < 16; ++r) {
      const int pxi = wv * 32 + (r & 3) + 8 * (r >> 2) + 4 * l5;
      const int y = y0 + (pxi >> 4), x = x0 + (pxi & 15);
      const float val = fmaxf(fmaf(acc[nt][r], inv, sh), 0.f);
      x2b[((size_t)((b * 96 + y) * 96 + x)) * 64 + oc] = f2bf(val);
    }
  }
}

extern "C" void kernel_launch(void* const* d_in, const int* in_sizes, int n_in,
                              void* d_out, int out_size, void* d_ws,
                              size_t ws_size, hipStream_t stream)
{
  (void)in_sizes; (void)n_in; (void)out_size; (void)ws_size;
  const float* features = (const float*)d_in[0];
  const float* coord_w  = (const float*)d_in[1];
  const float* coord_b  = (const float*)d_in[2];
  const float* bn1g = (const float*)d_in[3];
  const float* bn1b = (const float*)d_in[4];
  const float* bn1m = (const float*)d_in[5];
  const float* bn1v = (const float*)d_in[6];
  const float* off_w = (const float*)d_in[7];
  const float* off_b = (const float*)d_in[8];
  const float* dc_w  = (const float*)d_in[9];
  const float* bn2g = (const float*)d_in[10];
  const float* bn2b = (const float*)d_in[11];
  const float* bn2m = (const float*)d_in[12];
  const float* bn2v = (const float*)d_in[13];
  const float* r1_w = (const float*)d_in[14];
  const float* bn3g = (const float*)d_in[15];
  const float* bn3b = (const float*)d_in[16];
  const float* bn3m = (const float*)d_in[17];
  const float* bn3v = (const float*)d_in[18];
  const float* r2_w = (const float*)d_in[19];
  const float* bn4g = (const float*)d_in[20];
  const float* bn4b = (const float*)d_in[21];
  const float* bn4m = (const float*)d_in[22];
  const float* bn4v = (const float*)d_in[23];
  const float* out_w = (const float*)d_in[24];
  const float* out_b = (const float*)d_in[25];

  char* W = (char*)d_ws;
  float* offb = (float*)W;                         //  5,308,416 B
  u16*   x1b  = (u16*)(W + 5308416);               //  9,437,184 B
  u16*   x2b  = (u16*)(W + 14745600);
  u16*   x3b  = (u16*)(W + 24182784);
  u16*   wcf  = (u16*)(W + 33619968);
  u16*   wcc  = wcf + N_WCF;
  u16*   wof  = wcc + N_WCC;
  u16*   wdf  = wof + N_WOF;
  u16*   wr1  = wdf + N_W64;
  u16*   wr2  = wr1 + N_W64;

  prep_kernel<<<(N_ALLW + 255) / 256, 256, 0, stream>>>(
      coord_w, off_w, dc_w, r1_w, r2_w, wcf, wcc, wof, wdf, wr1, wr2);

  dim3 grid(3, 24, 8);   // 32x4 tiles
  dim3 gridD(6, 12, 8);  // 16x8 tiles (deform)

  coord_conv_kernel<<<grid, 256, 0, stream>>>(
      features, wcf, wcc, coord_b, bn1g, bn1b, bn1m, bn1v, x1b);
  conv64_kernel<1, 1><<<grid, 256, 0, stream>>>(
      x1b, wof, off_b, nullptr, nullptr, nullptr, nullptr, nullptr, nullptr,
      (void*)offb);
  deform_kernel<<<gridD, 256, 0, stream>>>(
      x1b, offb, wdf, bn2g, bn2b, bn2m, bn2v, x2b);
  conv64_kernel<2, 0><<<grid, 256, 0, stream>>>(
      x2b, wr1, nullptr, bn3g, bn3b, bn3m, bn3v, nullptr, nullptr, (void*)x3b);
  conv64_kernel<2, 2><<<grid, 256, 0, stream>>>(
      x3b, wr2, nullptr, bn4g, bn4b, bn4m, bn4v, out_w, out_b, d_out);
}